// Round 5
// baseline (214.715 us; speedup 1.0000x reference)
//
#include <hip/hip_runtime.h>
#include <math.h>

// Problem constants (B=4, S=2048, D_MODEL=512, H=8, DQ=64)
#define BATCH 4
#define SEQ   2048
#define DM    512
#define NH    8
#define DQ    64
#define BS    (BATCH*SEQ)     // 8192 rows
#define BPAD  72              // bf16 LDS row stride (144 B): fragment reads ~2-way (free)
#define APAD  72              // padded A-tile stride in qkv gemm

// q pre-scale: 1/sqrt(64) * log2(e), so softmax uses native 2^x (v_exp_f32)
#define QSCALE 0.18033688011112042f

typedef short  short8  __attribute__((ext_vector_type(8)));
typedef float  floatx4 __attribute__((ext_vector_type(4)));
typedef unsigned short ushort8 __attribute__((ext_vector_type(8)));

__device__ __forceinline__ unsigned short f2bf(float f) {
    unsigned u = __float_as_uint(f);
    unsigned r = (u + 0x7fffu + ((u >> 16) & 1u)) >> 16;   // RNE
    return (unsigned short)r;
}

__device__ __forceinline__ void async_copy16(const void* g, void* l) {
    __builtin_amdgcn_global_load_lds(
        (const __attribute__((address_space(1))) unsigned int*)g,
        (__attribute__((address_space(3))) unsigned int*)l, 16, 0, 0);
}

// ---------------------------------------------------------------------------
// convert_w: pack weights to bf16 B^T layout [n][k].
//   which 0..2: wt[which][h*64+d][dd] = W[h][dd][d]  (qkv projections)
//   which 3:    wo[o][c] = Wout[o][c]                 (already B^T)
// grid (256, 4).
// ---------------------------------------------------------------------------
__global__ __launch_bounds__(256) void convert_w_kernel(
    const float* __restrict__ Wq, const float* __restrict__ Wk,
    const float* __restrict__ Wv, const float* __restrict__ Wo,
    unsigned short* __restrict__ wt, unsigned short* __restrict__ wo)
{
    const int which = blockIdx.y;
    const int idx = blockIdx.x * 256 + threadIdx.x;   // 65536 per matrix
    if (which == 3) {
        float4 v = *(const float4*)(Wo + (size_t)idx * 4);
        ushort4 o;
        o.x = f2bf(v.x); o.y = f2bf(v.y); o.z = f2bf(v.z); o.w = f2bf(v.w);
        *(ushort4*)(wo + (size_t)idx * 4) = o;
    } else {
        const float* W = (which == 0) ? Wq : (which == 1) ? Wk : Wv;
        const int n   = idx >> 7;          // 0..511  (h*64+d)
        const int dd0 = (idx & 127) * 4;
        const int h = n >> 6, d = n & 63;
        ushort4 o;
        o.x = f2bf(W[((size_t)h * DM + dd0 + 0) * DQ + d]);
        o.y = f2bf(W[((size_t)h * DM + dd0 + 1) * DQ + d]);
        o.z = f2bf(W[((size_t)h * DM + dd0 + 2) * DQ + d]);
        o.w = f2bf(W[((size_t)h * DM + dd0 + 3) * DQ + d]);
        *(ushort4*)(wt + (size_t)which * (DM * DM) + (size_t)n * DM + dd0) = o;
    }
}

// ---------------------------------------------------------------------------
// qkv GEMM with fused fp32->bf16 conversion of x during A-staging.
// A = x fp32 [8192x512] (loaded directly), Bt = packed bf16 weights [512x512].
// 128x128 tile, BK=64. A staged manually into padded LDS (conflict-free
// fragment reads); B staged via global_load_lds (unpadded).
// Outputs: which 0 -> q*QSCALE bf16 [b,h,s,d]; 1 -> k bf16 [b,h,s,d];
//          2 -> v bf16 [b,h,d,s].
// grid (64, 4, 3), block 256.
// ---------------------------------------------------------------------------
__global__ __launch_bounds__(256) void qkv_gemm_kernel(
    const float* __restrict__ Xq, const float* __restrict__ Xk,
    const float* __restrict__ Xv, const unsigned short* __restrict__ wt,
    unsigned short* __restrict__ Oq, unsigned short* __restrict__ Ok,
    unsigned short* __restrict__ Ovt)
{
    __shared__ unsigned short As[128][APAD];   // padded: frag reads conflict-free
    __shared__ unsigned short Bs[128][64];     // global_load_lds target

    const int which = blockIdx.z;
    const float* X = (which == 0) ? Xq : (which == 1) ? Xk : Xv;
    const unsigned short* Bt = wt + (size_t)which * (DM * DM);

    const int m0 = blockIdx.x * 128;
    const int n0 = blockIdx.y * 128;
    const int t = threadIdx.x, w = t >> 6, lane = t & 63;
    const int quad = lane >> 4, qr = lane & 15;
    const int lr = lane >> 3;          // B-staging row within 8-row group
    const int lc = (lane & 7) * 8;     // B-staging col (bf16 elems)
    const int arow = t >> 4;           // A-staging: 16 rows per pass
    const int acol = (t & 15) * 4;     // A-staging: float4 column
    const int mw = 64 * (w >> 1), nw = 64 * (w & 1);

    floatx4 acc[4][4] = {};

    for (int k0 = 0; k0 < DM; k0 += 64) {
        // B: async DMA (4 chunks/thread)
        #pragma unroll
        for (int i = 0; i < 4; ++i) {
            const int row = i * 32 + w * 8;
            async_copy16(Bt + (size_t)(n0 + row + lr) * DM + k0 + lc, &Bs[row][0]);
        }
        // A: fp32 load + convert + manual staging (8 passes of 16 rows)
        #pragma unroll
        for (int i = 0; i < 8; ++i) {
            const int row = i * 16 + arow;
            float4 x4 = *(const float4*)(X + (size_t)(m0 + row) * DM + k0 + acol);
            ushort4 o;
            o.x = f2bf(x4.x); o.y = f2bf(x4.y); o.z = f2bf(x4.z); o.w = f2bf(x4.w);
            *(ushort4*)&As[row][acol] = o;
        }
        __syncthreads();
        #pragma unroll
        for (int kh = 0; kh < 2; ++kh) {
            short8 af[4], bf[4];
            #pragma unroll
            for (int si = 0; si < 4; ++si)
                af[si] = *(const short8*)&As[mw + 16 * si + qr][kh * 32 + quad * 8];
            #pragma unroll
            for (int sj = 0; sj < 4; ++sj)
                bf[sj] = *(const short8*)&Bs[nw + 16 * sj + qr][kh * 32 + quad * 8];
            #pragma unroll
            for (int si = 0; si < 4; ++si)
                #pragma unroll
                for (int sj = 0; sj < 4; ++sj)
                    acc[si][sj] = __builtin_amdgcn_mfma_f32_16x16x32_bf16(
                        af[si], bf[sj], acc[si][sj], 0, 0, 0);
        }
        __syncthreads();
    }

    const float osc = (which == 0) ? QSCALE : 1.0f;
    if (which < 2) {
        unsigned short* O = (which == 0) ? Oq : Ok;
        #pragma unroll
        for (int si = 0; si < 4; ++si) {
            #pragma unroll
            for (int sj = 0; sj < 4; ++sj) {
                const int col = n0 + nw + 16 * sj + qr;
                const int h = col >> 6, d = col & 63;
                #pragma unroll
                for (int r = 0; r < 4; ++r) {
                    const int row = m0 + mw + 16 * si + quad * 4 + r;
                    const int b = row >> 11, s = row & (SEQ - 1);
                    O[((size_t)(b * NH + h) * SEQ + s) * DQ + d] = f2bf(acc[si][sj][r] * osc);
                }
            }
        }
    } else {
        #pragma unroll
        for (int si = 0; si < 4; ++si) {
            #pragma unroll
            for (int sj = 0; sj < 4; ++sj) {
                const int col = n0 + nw + 16 * sj + qr;
                const int h = col >> 6, d = col & 63;
                #pragma unroll
                for (int r = 0; r < 4; ++r) {
                    const int row = m0 + mw + 16 * si + quad * 4 + r;
                    const int b = row >> 11, s = row & (SEQ - 1);
                    Ovt[((size_t)(b * NH + h) * DQ + d) * SEQ + s] = f2bf(acc[si][sj][r]);
                }
            }
        }
    }
}

// ---------------------------------------------------------------------------
// out GEMM: bf16 MFMA. A = heads bf16 [8192x512] (flat view == reference
// reshape), Bt = Wout bf16 [o][c]. Output fp32 d_out [8192x512].
// grid (64, 4), block 256.
// ---------------------------------------------------------------------------
__global__ __launch_bounds__(256) void out_gemm_kernel(
    const unsigned short* __restrict__ A, const unsigned short* __restrict__ Bt,
    float* __restrict__ C)
{
    __shared__ unsigned short As[128][64];
    __shared__ unsigned short Bs[128][64];

    const int m0 = blockIdx.x * 128;
    const int n0 = blockIdx.y * 128;
    const int t = threadIdx.x, w = t >> 6, lane = t & 63;
    const int quad = lane >> 4, qr = lane & 15;
    const int lr = lane >> 3;
    const int lc = (lane & 7) * 8;
    const int mw = 64 * (w >> 1), nw = 64 * (w & 1);

    floatx4 acc[4][4] = {};

    for (int k0 = 0; k0 < DM; k0 += 64) {
        #pragma unroll
        for (int i = 0; i < 4; ++i) {
            const int row = i * 32 + w * 8;
            async_copy16(A  + (size_t)(m0 + row + lr) * DM + k0 + lc, &As[row][0]);
            async_copy16(Bt + (size_t)(n0 + row + lr) * DM + k0 + lc, &Bs[row][0]);
        }
        __syncthreads();
        #pragma unroll
        for (int kh = 0; kh < 2; ++kh) {
            short8 af[4], bf[4];
            #pragma unroll
            for (int si = 0; si < 4; ++si)
                af[si] = *(const short8*)&As[mw + 16 * si + qr][kh * 32 + quad * 8];
            #pragma unroll
            for (int sj = 0; sj < 4; ++sj)
                bf[sj] = *(const short8*)&Bs[nw + 16 * sj + qr][kh * 32 + quad * 8];
            #pragma unroll
            for (int si = 0; si < 4; ++si)
                #pragma unroll
                for (int sj = 0; sj < 4; ++sj)
                    acc[si][sj] = __builtin_amdgcn_mfma_f32_16x16x32_bf16(
                        af[si], bf[sj], acc[si][sj], 0, 0, 0);
        }
        __syncthreads();
    }

    #pragma unroll
    for (int si = 0; si < 4; ++si) {
        #pragma unroll
        for (int sj = 0; sj < 4; ++sj) {
            const int col = n0 + nw + 16 * sj + qr;
            #pragma unroll
            for (int r = 0; r < 4; ++r) {
                const int row = m0 + mw + 16 * si + quad * 4 + r;
                C[(size_t)row * DM + col] = acc[si][sj][r];
            }
        }
    }
}

// ---------------------------------------------------------------------------
// flash attention v3: 128-row q-tile per block (4 waves x 32 q-rows, two
// hoisted Q/P fragments per wave) so K/V staging + fragment reads amortize
// over 2x the MFMA work. Fixed-reference softmax in base-2 (q pre-scaled by
// 0.125*log2e; exp2f = bare v_exp_f32). S^T orientation; K/V register-
// prefetched. LDS 55 KB -> 2 blocks/CU; grid 512 = all co-resident.
// grid = (16 q-tiles, 8 heads, 4 batch), block = 256.
// ---------------------------------------------------------------------------
__global__ __launch_bounds__(256) void attn_kernel(
    const unsigned short* __restrict__ Qp, const unsigned short* __restrict__ Kp,
    const unsigned short* __restrict__ Vtp, unsigned short* __restrict__ Hd)
{
    __shared__ unsigned short Qs[128][BPAD];  // [s][d]
    __shared__ unsigned short Ks[64][BPAD];   // [kv][d]
    __shared__ unsigned short Vts[64][BPAD];  // [d][kv]
    __shared__ unsigned short Ps[128][BPAD];  // [q-row][kv] bf16

    const int s0 = blockIdx.x * 128;
    const int h  = blockIdx.y;
    const int b  = blockIdx.z;
    const size_t bh    = (size_t)(b * NH + h);
    const size_t base  = bh * SEQ * DQ;       // [b,h,s,d]
    const size_t vbase = bh * DQ * SEQ;       // [b,h,d,s]

    const int t    = threadIdx.x;
    const int w    = t >> 6;
    const int lane = t & 63;
    const int quad = lane >> 4;
    const int qr   = lane & 15;

    // ---- stage Q tile (128 x 64): 4 ushort8 chunks per thread ----
    {
        const unsigned short* g = Qp + base + (size_t)s0 * DQ;
        #pragma unroll
        for (int i = 0; i < 4; ++i) {
            const int c = t + 256 * i;        // 0..1023
            const int row = c >> 3, col8 = (c & 7) * 8;
            *(ushort8*)&Qs[row][col8] = *(const ushort8*)(g + row * DQ + col8);
        }
    }
    __syncthreads();
    short8 aq[2][2];
    #pragma unroll
    for (int tq = 0; tq < 2; ++tq) {
        aq[tq][0] = *(const short8*)&Qs[32 * w + 16 * tq + qr][quad * 8];
        aq[tq][1] = *(const short8*)&Qs[32 * w + 16 * tq + qr][quad * 8 + 32];
    }

    floatx4 acc_o[2][4] = {};
    float l_lane[2] = {0.f, 0.f};

    // ---- prefetch first K/V tile into registers ----
    ushort8 kreg[2], vreg[2];
    {
        const unsigned short* gk = Kp + base;
        const unsigned short* gv = Vtp + vbase;
        #pragma unroll
        for (int i = 0; i < 2; ++i) {
            const int c = t + 256 * i;
            const int row = c >> 3, col8 = (c & 7) * 8;
            kreg[i] = *(const ushort8*)(gk + row * DQ + col8);
            vreg[i] = *(const ushort8*)(gv + (size_t)row * SEQ + col8);
        }
    }

    for (int kt = 0; kt < SEQ; kt += 64) {
        __syncthreads();   // prev iteration's reads of Ks/Vts complete
        #pragma unroll
        for (int i = 0; i < 2; ++i) {
            const int c = t + 256 * i;
            const int row = c >> 3, col8 = (c & 7) * 8;
            *(ushort8*)&Ks[row][col8]  = kreg[i];
            *(ushort8*)&Vts[row][col8] = vreg[i];
        }
        __syncthreads();

        // issue next tile's global loads (overlap with MFMA below)
        if (kt + 64 < SEQ) {
            const unsigned short* gk = Kp + base + (size_t)(kt + 64) * DQ;
            const unsigned short* gv = Vtp + vbase + (kt + 64);
            #pragma unroll
            for (int i = 0; i < 2; ++i) {
                const int c = t + 256 * i;
                const int row = c >> 3, col8 = (c & 7) * 8;
                kreg[i] = *(const ushort8*)(gk + row * DQ + col8);
                vreg[i] = *(const ushort8*)(gv + (size_t)row * SEQ + col8);
            }
        }

        // ---- S^T = K @ Q^T per kv-subtile si, both q-subtiles; exp2; pack P.
        // C-layout: lane holds kv = 16si+quad*4+{0..3}, qrow = 32w+16tq+qr.
        #pragma unroll
        for (int si = 0; si < 4; ++si) {
            const short8 ak0 = *(const short8*)&Ks[16 * si + qr][quad * 8];
            const short8 ak1 = *(const short8*)&Ks[16 * si + qr][quad * 8 + 32];
            #pragma unroll
            for (int tq = 0; tq < 2; ++tq) {
                floatx4 z = {0.f, 0.f, 0.f, 0.f};
                z = __builtin_amdgcn_mfma_f32_16x16x32_bf16(ak0, aq[tq][0], z, 0, 0, 0);
                z = __builtin_amdgcn_mfma_f32_16x16x32_bf16(ak1, aq[tq][1], z, 0, 0, 0);
                const float p0 = exp2f(z[0]), p1 = exp2f(z[1]);
                const float p2 = exp2f(z[2]), p3 = exp2f(z[3]);
                l_lane[tq] += (p0 + p1) + (p2 + p3);
                ushort4 pk;
                pk.x = f2bf(p0); pk.y = f2bf(p1); pk.z = f2bf(p2); pk.w = f2bf(p3);
                *(ushort4*)&Ps[32 * w + 16 * tq + qr][16 * si + quad * 4] = pk;
            }
        }

        // ---- PV: acc_o[tq][c] += P @ V (wave-private Ps, no barrier) ----
        short8 ap[2][2];
        #pragma unroll
        for (int tq = 0; tq < 2; ++tq) {
            ap[tq][0] = *(const short8*)&Ps[32 * w + 16 * tq + qr][quad * 8];
            ap[tq][1] = *(const short8*)&Ps[32 * w + 16 * tq + qr][quad * 8 + 32];
        }
        #pragma unroll
        for (int c = 0; c < 4; ++c) {
            const short8 bv0 = *(const short8*)&Vts[16 * c + qr][quad * 8];
            const short8 bv1 = *(const short8*)&Vts[16 * c + qr][quad * 8 + 32];
            #pragma unroll
            for (int tq = 0; tq < 2; ++tq) {
                acc_o[tq][c] = __builtin_amdgcn_mfma_f32_16x16x32_bf16(
                    ap[tq][0], bv0, acc_o[tq][c], 0, 0, 0);
                acc_o[tq][c] = __builtin_amdgcn_mfma_f32_16x16x32_bf16(
                    ap[tq][1], bv1, acc_o[tq][c], 0, 0, 0);
            }
        }
    }

    // ---- normalize and store (bf16 heads) ----
    #pragma unroll
    for (int tq = 0; tq < 2; ++tq) {
        float l = l_lane[tq];
        l += __shfl_xor(l, 16);
        l += __shfl_xor(l, 32);          // every lane: full l for qrow 32w+16tq+qr
        float inv_l[4];
        #pragma unroll
        for (int r = 0; r < 4; ++r)
            inv_l[r] = 1.0f / __shfl(l, quad * 4 + r);
        #pragma unroll
        for (int c = 0; c < 4; ++c)
            #pragma unroll
            for (int r = 0; r < 4; ++r)
                Hd[base + (size_t)(s0 + 32 * w + 16 * tq + quad * 4 + r) * DQ + 16 * c + qr] =
                    f2bf(acc_o[tq][c][r] * inv_l[r]);
    }
}

// ---------------------------------------------------------------------------
// kernel_launch
// Workspace (ushort units):
//   wt:    0        (3 x 262144)    qkv weights bf16, B^T [h*64+d][dd]
//   wo:    786432   (262144)        Wout bf16 [o][c]
//   q_ws:  1048576  (4194304)       q*QSCALE bf16 [b,h,s,d]
//   k_ws:  5242880  (4194304)       k bf16 [b,h,s,d]
//   vt_ws: 9437184  (4194304)       v bf16 [b,h,d,s]
//   h_ws:  13631488 (4194304)       heads bf16 (flat GEMM-A view)
// total ~34 MB
// ---------------------------------------------------------------------------
extern "C" void kernel_launch(void* const* d_in, const int* in_sizes, int n_in,
                              void* d_out, int out_size, void* d_ws, size_t ws_size,
                              hipStream_t stream) {
    const float* xq = (const float*)d_in[0];
    const float* xk = (const float*)d_in[1];
    const float* xv = (const float*)d_in[2];
    const float* Qw = (const float*)d_in[3];
    const float* Kw = (const float*)d_in[4];
    const float* Vw = (const float*)d_in[5];
    const float* Wo = (const float*)d_in[6];
    float* out = (float*)d_out;

    unsigned short* ws = (unsigned short*)d_ws;
    unsigned short* wt    = ws;
    unsigned short* wo    = ws + (size_t)786432;
    unsigned short* q_ws  = ws + (size_t)1048576;
    unsigned short* k_ws  = ws + (size_t)5242880;
    unsigned short* vt_ws = ws + (size_t)9437184;
    unsigned short* h_ws  = ws + (size_t)13631488;

    convert_w_kernel<<<dim3(256, 4), 256, 0, stream>>>(Qw, Kw, Vw, Wo, wt, wo);
    qkv_gemm_kernel<<<dim3(64, 4, 3), 256, 0, stream>>>(xq, xk, xv, wt, q_ws, k_ws, vt_ws);
    attn_kernel<<<dim3(SEQ / 128, NH, BATCH), 256, 0, stream>>>(q_ws, k_ws, vt_ws, h_ws);
    out_gemm_kernel<<<dim3(64, 4), 256, 0, stream>>>(h_ws, wo, out);
}